// Round 2
// baseline (902.953 us; speedup 1.0000x reference)
//
#include <hip/hip_runtime.h>

// ---------------------------------------------------------------------------
// PanguProMoE decoder layer, MI355X (gfx950).
// Precision: pre-router chain (qkv GEMM, attention, o-proj) in split-f16
// ("f16x2": x = hi + lo/1024, 3 MFMAs/tile) for fp32-grade router logits.
// Post-router MoE in plain f16 MFMA. RoPE angles in double.
// R2 changes: attn LPT-complementary block map + reg-prefetch staging +
// defer-max; GEMMs use global_load_lds (linear LDS, BK=32); transposes
// vectorized (half8 writes); V^T produced by tiled transpose.
// ---------------------------------------------------------------------------

typedef _Float16 half_t;
typedef _Float16 half8 __attribute__((ext_vector_type(8)));
typedef float    f32x4 __attribute__((ext_vector_type(4)));
typedef float    floatx4 __attribute__((ext_vector_type(4)));

#define T_TOK 2048
#define HIDN  2048
#define NH    16
#define NKVH  4
#define HD    128
#define QKV_N 3072
#define NEXP  8

#define MFMA16(a,b,c) __builtin_amdgcn_mfma_f32_16x16x32_f16(a,b,c,0,0,0)

__device__ __forceinline__ void gload_lds16(const half_t* g, half_t* l) {
    __builtin_amdgcn_global_load_lds(
        (const __attribute__((address_space(1))) void*)g,
        (__attribute__((address_space(3))) void*)l, 16, 0, 0);
}

// ---------------------------------------------------------------------------
// rmsnorm over HIDN cols, write split f16 (lo optional)
// ---------------------------------------------------------------------------
__global__ __launch_bounds__(256)
void rmsnorm_split_k(const float* __restrict__ x, const float* __restrict__ w,
                     half_t* __restrict__ hi, half_t* __restrict__ lo)
{
    const int row = blockIdx.x, tid = threadIdx.x;
    const float* xr = x + (size_t)row * HIDN;
    floatx4 v0 = *(const floatx4*)(xr + tid * 8);
    floatx4 v1 = *(const floatx4*)(xr + tid * 8 + 4);
    float ss = v0[0]*v0[0] + v0[1]*v0[1] + v0[2]*v0[2] + v0[3]*v0[3]
             + v1[0]*v1[0] + v1[1]*v1[1] + v1[2]*v1[2] + v1[3]*v1[3];
    for (int o = 32; o; o >>= 1) ss += __shfl_down(ss, o);
    __shared__ float red[4];
    if ((tid & 63) == 0) red[tid >> 6] = ss;
    __syncthreads();
    ss = red[0] + red[1] + red[2] + red[3];
    float rs = rsqrtf(ss * (1.0f / HIDN) + 1e-6f);
    floatx4 w0 = *(const floatx4*)(w + tid * 8);
    floatx4 w1 = *(const floatx4*)(w + tid * 8 + 4);
    float vv[8] = { v0[0]*w0[0], v0[1]*w0[1], v0[2]*w0[2], v0[3]*w0[3],
                    v1[0]*w1[0], v1[1]*w1[1], v1[2]*w1[2], v1[3]*w1[3] };
    half8 hv, lv;
#pragma unroll
    for (int j = 0; j < 8; ++j) {
        float o = vv[j] * rs;
        half_t h = (half_t)o;
        hv[j] = h;
        lv[j] = (half_t)((o - (float)h) * 1024.0f);
    }
    *(half8*)(hi + (size_t)row * HIDN + tid * 8) = hv;
    if (lo) *(half8*)(lo + (size_t)row * HIDN + tid * 8) = lv;
}

// ---------------------------------------------------------------------------
// Transpose fp32 -> split f16: dst[n][k] = src[k][n]. 32x32 tile, half8 writes.
// ---------------------------------------------------------------------------
__global__ __launch_bounds__(256)
void transpose_split2(const float* __restrict__ src, half_t* __restrict__ dh,
                      half_t* __restrict__ dl, int sstride, int dstride)
{
    __shared__ float tile[32][36];
    const int n0 = blockIdx.x * 32, k0 = blockIdx.y * 32;
    const int tid = threadIdx.x;
    {
        int r = tid >> 3, c = (tid & 7) * 4;
        *(floatx4*)&tile[r][c] =
            *(const floatx4*)(src + (size_t)(k0 + r) * sstride + n0 + c);
    }
    __syncthreads();
    int n = tid & 31, g = tid >> 5, gg = g & 3;
    half8 hv;
    if (g < 4) {
#pragma unroll
        for (int j = 0; j < 8; ++j) hv[j] = (half_t)tile[gg * 8 + j][n];
        *(half8*)(dh + (size_t)(n0 + n) * dstride + k0 + gg * 8) = hv;
    } else {
#pragma unroll
        for (int j = 0; j < 8; ++j) {
            float v = tile[gg * 8 + j][n];
            half_t h = (half_t)v;
            hv[j] = (half_t)((v - (float)h) * 1024.0f);
        }
        *(half8*)(dl + (size_t)(n0 + n) * dstride + k0 + gg * 8) = hv;
    }
}

// ---------------------------------------------------------------------------
// Transpose fp32 -> single f16: dst[n][k] = src[k][n]. 32(k)x64(n) tile.
// ---------------------------------------------------------------------------
__global__ __launch_bounds__(256)
void transpose_f16(const float* __restrict__ src, half_t* __restrict__ dh,
                   int sstride, int dstride)
{
    __shared__ float tile[32][68];
    const int n0 = blockIdx.x * 64, k0 = blockIdx.y * 32;
    const int tid = threadIdx.x;
    {
        int r = tid >> 3, c = (tid & 7) * 4;
        const float* s = src + (size_t)(k0 + r) * sstride + n0;
        *(floatx4*)&tile[r][c]      = *(const floatx4*)(s + c);
        *(floatx4*)&tile[r][c + 32] = *(const floatx4*)(s + c + 32);
    }
    __syncthreads();
    int n = tid & 63, g = tid >> 6;   // g in 0..3
    half8 hv;
#pragma unroll
    for (int j = 0; j < 8; ++j) hv[j] = (half_t)tile[g * 8 + j][n];
    *(half8*)(dh + (size_t)(n0 + n) * dstride + k0 + g * 8) = hv;
}

// ---------------------------------------------------------------------------
// GEMM: C[M][N] = A[M][K] @ Bt[N][K]^T (+bias)(+res). f16 in, fp32 acc.
// SPLIT: (hi, lo*1024) pairs, 3 MFMAs/tile. 128x128 tile, BK=32, 4 waves.
// Staging via global_load_lds width=16 into linear [128][32] LDS (m97).
// ---------------------------------------------------------------------------
template<bool SPLIT>
__global__ __launch_bounds__(256, 2)
void gemm_f16(const half_t* __restrict__ Ah, const half_t* __restrict__ Al,
              const half_t* __restrict__ Bth, const half_t* __restrict__ Btl,
              const float* __restrict__ bias, const float* __restrict__ res,
              float* __restrict__ Cf, half_t* __restrict__ Ch,
              int M, int N, int K)
{
    constexpr int NBUF = SPLIT ? 2 : 1;
    __shared__ half_t As[NBUF][128 * 32];
    __shared__ half_t Bs[NBUF][128 * 32];
    const int tid = threadIdx.x, lane = tid & 63, wid = tid >> 6;
    const int l15 = lane & 15, l4 = lane >> 4;
    const int row0 = blockIdx.y * 128, col0 = blockIdx.x * 128;
    const int wr = (wid >> 1) * 64, wc = (wid & 1) * 64;
    f32x4 accM[4][4] = {}, accC[4][4] = {};
    const int srow = wid * 32;                 // wave-uniform staging base row
    const int lrw = lane >> 2, lcl = (lane & 3) * 8;

    for (int k0 = 0; k0 < K; k0 += 32) {
        __syncthreads();                       // prev compute done, LDS free
#pragma unroll
        for (int j = 0; j < 2; ++j) {
            const int r = srow + j * 16;
            const size_t ga = (size_t)(row0 + r + lrw) * K + k0 + lcl;
            const size_t gb = (size_t)(col0 + r + lrw) * K + k0 + lcl;
            gload_lds16(Ah + ga, &As[0][r * 32]);
            gload_lds16(Bth + gb, &Bs[0][r * 32]);
            if constexpr (SPLIT) {
                gload_lds16(Al + ga, &As[1][r * 32]);
                gload_lds16(Btl + gb, &Bs[1][r * 32]);
            }
        }
        __syncthreads();                       // vmcnt(0) drained before barrier
        half8 ah[4], al[4], bh[4], bl[4];
#pragma unroll
        for (int m = 0; m < 4; ++m) {
            int off = (wr + m * 16 + l15) * 32 + l4 * 8;
            ah[m] = *(const half8*)&As[0][off];
            if constexpr (SPLIT) al[m] = *(const half8*)&As[1][off];
        }
#pragma unroll
        for (int n = 0; n < 4; ++n) {
            int off = (wc + n * 16 + l15) * 32 + l4 * 8;
            bh[n] = *(const half8*)&Bs[0][off];
            if constexpr (SPLIT) bl[n] = *(const half8*)&Bs[1][off];
        }
#pragma unroll
        for (int m = 0; m < 4; ++m)
#pragma unroll
            for (int n = 0; n < 4; ++n) {
                accM[m][n] = MFMA16(ah[m], bh[n], accM[m][n]);
                if constexpr (SPLIT) {
                    accC[m][n] = MFMA16(ah[m], bl[n], accC[m][n]);
                    accC[m][n] = MFMA16(al[m], bh[n], accC[m][n]);
                }
            }
    }
#pragma unroll
    for (int m = 0; m < 4; ++m) {
#pragma unroll
        for (int n = 0; n < 4; ++n) {
            int gr0 = row0 + wr + m * 16 + l4 * 4;
            int gc  = col0 + wc + n * 16 + l15;
            float b = bias ? bias[gc] : 0.0f;
#pragma unroll
            for (int i = 0; i < 4; ++i) {
                float v = accM[m][n][i];
                if constexpr (SPLIT) v += accC[m][n][i] * (1.0f / 1024.0f);
                v += b;
                size_t idx = (size_t)(gr0 + i) * N + gc;
                if (res) v += res[idx];
                if (Cf) Cf[idx] = v;
                if (Ch) Ch[idx] = (half_t)v;
            }
        }
    }
}

// ---------------------------------------------------------------------------
// qkv post-processing: k-rmsnorm, RoPE on q/k (last 64 dims), Q pre-scaled by
// 128^-0.5, split-f16 outputs. (V handled by transpose_split2 separately.)
// ---------------------------------------------------------------------------
__global__ __launch_bounds__(256)
void qkv_prep(const float* __restrict__ qkv, const int* __restrict__ pos,
              const float* __restrict__ klnw,
              half_t* __restrict__ qh, half_t* __restrict__ ql,
              half_t* __restrict__ kh, half_t* __restrict__ kl)
{
    const int t = blockIdx.x, tid = threadIdx.x, lane = tid & 63, wid = tid >> 6;
    const float* row = qkv + (size_t)t * QKV_N;
    __shared__ float cs[32], sn[32];
    if (tid < 32) {
        double freq = exp((double)tid * -0.28782313662425572);  // -ln(1e4)/32
        double ang = (double)pos[t] * freq;
        const double twopi = 6.283185307179586476925286766559;
        ang -= twopi * floor(ang * (1.0 / twopi));
        float a = (float)ang;
        cs[tid] = cosf(a);
        sn[tid] = sinf(a);
    }
    __syncthreads();

    const float qscale = 0.08838834764831845f;   // 128^-0.5
    // ---- Q: thread -> (head = tid>>4, d0 = (tid&15)*8)
    {
        const int hh = tid >> 4, d0 = (tid & 15) * 8;
        const float* qrow = row + hh * HD;
        float outv[8];
        if (d0 < 64) {
#pragma unroll
            for (int j = 0; j < 8; ++j) outv[j] = qrow[d0 + j];
        } else if (d0 < 96) {
            int j0 = d0 - 64;
#pragma unroll
            for (int j = 0; j < 8; ++j) {
                int jj = j0 + j;
                outv[j] = qrow[64 + jj] * cs[jj] - qrow[96 + jj] * sn[jj];
            }
        } else {
            int j0 = d0 - 96;
#pragma unroll
            for (int j = 0; j < 8; ++j) {
                int jj = j0 + j;
                outv[j] = qrow[64 + jj] * sn[jj] + qrow[96 + jj] * cs[jj];
            }
        }
        half8 hv, lv;
#pragma unroll
        for (int j = 0; j < 8; ++j) {
            float o = outv[j] * qscale;
            half_t h = (half_t)o;
            hv[j] = h;
            lv[j] = (half_t)((o - (float)h) * 1024.0f);
        }
        size_t base = (size_t)t * (NH * HD) + hh * HD + d0;
        *(half8*)(qh + base) = hv;
        *(half8*)(ql + base) = lv;
    }

    // ---- K: wave wid handles kv-head wid; rmsnorm(128) then rope
    {
        const float* krow = row + NH * HD + wid * HD;
        float a0 = krow[lane], a1 = krow[64 + lane];
        float ss = a0 * a0 + a1 * a1;
        for (int o = 32; o; o >>= 1) ss += __shfl_down(ss, o);
        ss = __shfl(ss, 0);
        float rs = rsqrtf(ss * (1.0f / HD) + 1e-6f);
        float n0 = a0 * rs * klnw[lane];
        float n1 = a1 * rs * klnw[64 + lane];
        float other = __shfl_xor(n1, 32);
        int j = lane & 31;
        float o1 = (lane < 32) ? (n1 * cs[j] - other * sn[j])
                               : (other * sn[j] + n1 * cs[j]);
        size_t base = (size_t)t * (NKVH * HD) + wid * HD;
        half_t h;
        h = (half_t)n0; kh[base + lane] = h;
        kl[base + lane] = (half_t)((n0 - (float)h) * 1024.0f);
        h = (half_t)o1; kh[base + 64 + lane] = h;
        kl[base + 64 + lane] = (half_t)((o1 - (float)h) * 1024.0f);
    }
}

// ---------------------------------------------------------------------------
// Flash attention, causal GQA, split-f16 MFMA. 4 waves x 16 q-rows, KVBLK=32.
// LPT-complementary block map: first 256 blocks qblk descending (heads 0-7),
// next 256 ascending (heads 8-15) -> each CU's pair sums to uniform work.
// Reg-prefetch staging (next tile's global loads overlap compute); defer-max.
// ---------------------------------------------------------------------------
__global__ __launch_bounds__(256, 2)
void attn_kernel(const half_t* __restrict__ qh, const half_t* __restrict__ ql,
                 const half_t* __restrict__ kh, const half_t* __restrict__ kl,
                 const half_t* __restrict__ vth, const half_t* __restrict__ vtl,
                 half_t* __restrict__ oh, half_t* __restrict__ ol)
{
    const int bid = blockIdx.y * 32 + blockIdx.x;
    int qblk, h;
    if (bid < 256) { qblk = 31 - (bid & 31); h = bid >> 5; }
    else           { qblk = (bid - 256) & 31; h = 8 + ((bid - 256) >> 5); }
    const int kvh = h >> 2;
    const int tid = threadIdx.x, lane = tid & 63, wid = tid >> 6;
    const int q0 = qblk * 64 + wid * 16;
    const int l15 = lane & 15, l4 = lane >> 4;

    __shared__ half_t Ksh[32][136], Ksl[32][136];
    __shared__ half_t Vsh[128][40], Vsl[128][40];
    __shared__ half_t Ph[4][16][40], Pl[4][16][40];

    half8 qfh[4], qfl[4];
    {
        const size_t qb = (size_t)(q0 + l15) * (NH * HD) + h * HD + l4 * 8;
#pragma unroll
        for (int c = 0; c < 4; ++c) {
            qfh[c] = *(const half8*)(qh + qb + c * 32);
            qfl[c] = *(const half8*)(ql + qb + c * 32);
        }
    }

    f32x4 om[8] = {}, oc[8] = {};
    float mrow[4] = { -1e30f, -1e30f, -1e30f, -1e30f };
    float lrow[4] = {};

    // staging decomposition (per-thread)
    const int kr = tid >> 4, kc = (tid & 15) * 8;
    const int vd = tid >> 2, vc = (tid & 3) * 8;
    uint4 rkh[2], rkl[2], rvh[2], rvl[2];

    const int kvend = qblk * 64 + 64;

#define LOAD_TILE(KV0)                                                        \
    {                                                                         \
        _Pragma("unroll")                                                     \
        for (int it = 0; it < 2; ++it) {                                      \
            size_t sk = (size_t)((KV0) + kr + it * 16) * (NKVH * HD)          \
                        + kvh * HD + kc;                                      \
            rkh[it] = *(const uint4*)(kh + sk);                               \
            rkl[it] = *(const uint4*)(kl + sk);                               \
            size_t sv = (size_t)(kvh * HD + vd + it * 64) * T_TOK + (KV0) + vc;\
            rvh[it] = *(const uint4*)(vth + sv);                              \
            rvl[it] = *(const uint4*)(vtl + sv);                              \
        }                                                                     \
    }

    LOAD_TILE(0);
    for (int kv0 = 0; kv0 < kvend; kv0 += 32) {
#pragma unroll
        for (int it = 0; it < 2; ++it) {       // regs -> LDS
            *(uint4*)&Ksh[kr + it * 16][kc] = rkh[it];
            *(uint4*)&Ksl[kr + it * 16][kc] = rkl[it];
            *(uint4*)&Vsh[vd + it * 64][vc] = rvh[it];
            *(uint4*)&Vsl[vd + it * 64][vc] = rvl[it];
        }
        __syncthreads();
        if (kv0 + 32 < kvend) LOAD_TILE(kv0 + 32);   // overlaps compute

        f32x4 sf[2];
#pragma unroll
        for (int t2 = 0; t2 < 2; ++t2) {       // S = Q K^T (pre-scaled Q)
            f32x4 s = {}, sc = {};
#pragma unroll
            for (int c = 0; c < 4; ++c) {
                half8 bh = *(const half8*)&Ksh[t2 * 16 + l15][c * 32 + l4 * 8];
                half8 bl = *(const half8*)&Ksl[t2 * 16 + l15][c * 32 + l4 * 8];
                s  = MFMA16(qfh[c], bh, s);
                sc = MFMA16(qfh[c], bl, sc);
                sc = MFMA16(qfl[c], bh, sc);
            }
            sf[t2] = s + sc * (1.0f / 1024.0f);
        }

        float pmax[4];
#pragma unroll
        for (int i = 0; i < 4; ++i) {
            const int qg = q0 + l4 * 4 + i;
#pragma unroll
            for (int t2 = 0; t2 < 2; ++t2) {
                int kvg = kv0 + t2 * 16 + l15;
                if (kvg > qg) sf[t2][i] = -1e30f;
            }
            float mx = fmaxf(sf[0][i], sf[1][i]);
#pragma unroll
            for (int o = 1; o < 16; o <<= 1) mx = fmaxf(mx, __shfl_xor(mx, o));
            pmax[i] = mx;
        }
        float dm = fmaxf(fmaxf(pmax[0] - mrow[0], pmax[1] - mrow[1]),
                         fmaxf(pmax[2] - mrow[2], pmax[3] - mrow[3]));
        if (__any(dm > 6.0f)) {                // defer-max: rescale rarely
#pragma unroll
            for (int i = 0; i < 4; ++i) {
                float mnew = fmaxf(mrow[i], pmax[i]);
                float resc = expf(mrow[i] - mnew);
                lrow[i] *= resc;
#pragma unroll
                for (int c8 = 0; c8 < 8; ++c8) {
                    om[c8][i] *= resc; oc[c8][i] *= resc;
                }
                mrow[i] = mnew;
            }
        }
#pragma unroll
        for (int i = 0; i < 4; ++i) {
            float p0 = expf(sf[0][i] - mrow[i]);
            float p1 = expf(sf[1][i] - mrow[i]);
            lrow[i] += p0 + p1;
            half_t hh;
            hh = (half_t)p0;
            Ph[wid][l4 * 4 + i][l15] = hh;
            Pl[wid][l4 * 4 + i][l15] = (half_t)((p0 - (float)hh) * 1024.0f);
            hh = (half_t)p1;
            Ph[wid][l4 * 4 + i][16 + l15] = hh;
            Pl[wid][l4 * 4 + i][16 + l15] = (half_t)((p1 - (float)hh) * 1024.0f);
        }

        half8 pah = *(const half8*)&Ph[wid][l15][l4 * 8];
        half8 pal = *(const half8*)&Pl[wid][l15][l4 * 8];
#pragma unroll
        for (int c8 = 0; c8 < 8; ++c8) {       // O += P V
            half8 vh = *(const half8*)&Vsh[c8 * 16 + l15][l4 * 8];
            half8 vl = *(const half8*)&Vsl[c8 * 16 + l15][l4 * 8];
            om[c8] = MFMA16(pah, vh, om[c8]);
            oc[c8] = MFMA16(pah, vl, oc[c8]);
            oc[c8] = MFMA16(pal, vh, oc[c8]);
        }
        __syncthreads();
    }
#undef LOAD_TILE

#pragma unroll
    for (int i = 0; i < 4; ++i)
#pragma unroll
        for (int o = 1; o < 16; o <<= 1) lrow[i] += __shfl_xor(lrow[i], o);

#pragma unroll
    for (int c8 = 0; c8 < 8; ++c8) {
#pragma unroll
        for (int i = 0; i < 4; ++i) {
            float v = (om[c8][i] + oc[c8][i] * (1.0f / 1024.0f)) / lrow[i];
            size_t idx = (size_t)(q0 + l4 * 4 + i) * (NH * HD) + h * HD + c8 * 16 + l15;
            half_t hh = (half_t)v;
            oh[idx] = hh;
            ol[idx] = (half_t)((v - (float)hh) * 1024.0f);
        }
    }
}

// ---------------------------------------------------------------------------
// Router: h2 = rmsnorm(x2, ln2w); logits = h2 @ rw; top-2 normalized weights.
// ---------------------------------------------------------------------------
__global__ __launch_bounds__(256)
void router_kernel(const float* __restrict__ x2, const float* __restrict__ ln2w,
                   const float* __restrict__ rw, float* __restrict__ combine)
{
    const int t = blockIdx.x, tid = threadIdx.x;
    const float* xr = x2 + (size_t)t * HIDN;
    float vals[8];
    float ss = 0.0f;
#pragma unroll
    for (int i = 0; i < 8; ++i) {
        vals[i] = xr[tid + i * 256];
        ss += vals[i] * vals[i];
    }
    for (int o = 32; o; o >>= 1) ss += __shfl_down(ss, o);
    __shared__ float red[4];
    if ((tid & 63) == 0) red[tid >> 6] = ss;
    __syncthreads();
    ss = red[0] + red[1] + red[2] + red[3];
    float rs = rsqrtf(ss * (1.0f / HIDN) + 1e-6f);

    float acc[NEXP] = {};
#pragma unroll
    for (int i = 0; i < 8; ++i) {
        int c = tid + i * 256;
        float hv = vals[i] * rs * ln2w[c];
        const float* wr = rw + (size_t)c * NEXP;
#pragma unroll
        for (int e = 0; e < NEXP; ++e) acc[e] += hv * wr[e];
    }
#pragma unroll
    for (int e = 0; e < NEXP; ++e)
        for (int o = 32; o; o >>= 1) acc[e] += __shfl_down(acc[e], o);
    __shared__ float red8[4][NEXP];
    if ((tid & 63) == 0)
#pragma unroll
        for (int e = 0; e < NEXP; ++e) red8[tid >> 6][e] = acc[e];
    __syncthreads();
    if (tid == 0) {
        float lg[NEXP];
#pragma unroll
        for (int e = 0; e < NEXP; ++e)
            lg[e] = red8[0][e] + red8[1][e] + red8[2][e] + red8[3][e];
        int i1 = 0;
        for (int e = 1; e < NEXP; ++e) if (lg[e] > lg[i1]) i1 = e;
        int i2 = (i1 == 0) ? 1 : 0;
        for (int e = 0; e < NEXP; ++e) if (e != i1 && lg[e] > lg[i2]) i2 = e;
        float mx = lg[i1];
        float p1 = expf(lg[i1] - mx), p2 = expf(lg[i2] - mx);
        float inv = 1.0f / (p1 + p2);
        float* cr = combine + (size_t)t * NEXP;
#pragma unroll
        for (int e = 0; e < NEXP; ++e) cr[e] = 0.0f;
        cr[i1] = p1 * inv;
        cr[i2] = p2 * inv;
    }
}

// ---------------------------------------------------------------------------
// MoE activation: Abig[t][n] = scale * silu(G[t][n]) * U[t][n]
// ---------------------------------------------------------------------------
__global__ __launch_bounds__(256)
void moe_act(const half_t* __restrict__ GU, const float* __restrict__ comb,
             half_t* __restrict__ Abig)
{
    int idx = blockIdx.x * 256 + threadIdx.x;
    int t = idx / 640, c8 = idx % 640;
    int n = c8 * 8;
    half8 g8 = *(const half8*)(GU + (size_t)t * 10240 + n);
    half8 u8 = *(const half8*)(GU + (size_t)t * 10240 + 5120 + n);
    float sc = (n < 1024) ? 1.0f : comb[(size_t)t * NEXP + ((n - 1024) >> 9)];
    half8 o8;
#pragma unroll
    for (int j = 0; j < 8; ++j) {
        float g = (float)g8[j], u = (float)u8[j];
        float s = g / (1.0f + expf(-g));
        o8[j] = (half_t)(s * u * sc);
    }
    *(half8*)(Abig + (size_t)t * 5120 + n) = o8;
}

// ---------------------------------------------------------------------------
extern "C" void kernel_launch(void* const* d_in, const int* in_sizes, int n_in,
                              void* d_out, int out_size, void* d_ws, size_t ws_size,
                              hipStream_t stream)
{
    (void)in_sizes; (void)n_in; (void)out_size; (void)ws_size;
    const float* x    = (const float*)d_in[0];
    const int*   pos  = (const int*)  d_in[1];
    const float* ln1w = (const float*)d_in[2];
    const float* qkvw = (const float*)d_in[3];
    const float* qkvb = (const float*)d_in[4];
    const float* klnw = (const float*)d_in[5];
    const float* ow   = (const float*)d_in[6];
    const float* ln2w = (const float*)d_in[7];
    const float* rw   = (const float*)d_in[8];
    const float* w1   = (const float*)d_in[9];
    const float* w2   = (const float*)d_in[10];
    const float* w3   = (const float*)d_in[11];
    const float* sw1  = (const float*)d_in[12];
    const float* sw2  = (const float*)d_in[13];
    const float* sw3  = (const float*)d_in[14];
    float* out = (float*)d_out;

    // ---- workspace arena (phase-overlapped; total 142,671,872 B) ----
    char* ws = (char*)d_ws;
    const size_t AB = 16842752;
    float*  x2      = (float*)(ws);
    float*  combine = (float*)(ws + 16777216);
    half_t* h_hi    = (half_t*)(ws + AB);
    half_t* h_lo    = (half_t*)(ws + AB + 8388608);
    half_t* qkvwt_h = (half_t*)(ws + AB + 16777216);
    half_t* qkvwt_l = (half_t*)(ws + AB + 29360128);
    float*  qkv     = (float*)(ws + AB + 41943040);
    half_t* q_h     = (half_t*)(ws + AB + 67108864);
    half_t* q_l     = (half_t*)(ws + AB + 75497472);
    half_t* k_h     = (half_t*)(ws + AB + 83886080);
    half_t* k_l     = (half_t*)(ws + AB + 85983232);
    half_t* vt_h    = (half_t*)(ws + AB + 88080384);
    half_t* vt_l    = (half_t*)(ws + AB + 90177536);
    half_t* attn_h  = (half_t*)(ws + AB);             // reuse h_hi
    half_t* attn_l  = (half_t*)(ws + AB + 8388608);   // reuse h_lo
    half_t* owt_h   = (half_t*)(ws + AB + 16777216);  // reuse qkvwt
    half_t* owt_l   = (half_t*)(ws + AB + 25165824);
    half_t* h2      = (half_t*)(ws + AB + 33554432);
    half_t* W13t    = (half_t*)(ws + AB + 41943040);  // reuse qkv + q (dead)
    half_t* GU      = (half_t*)(ws + AB + 83886080);  // reuse k/vt (dead)
    half_t* Abig    = (half_t*)(ws + AB);             // reuse attn (dead)
    half_t* W2t     = (half_t*)(ws + AB + 41943040);  // reuse W13t (dead)

    dim3 b256(256);

    // 1. h = rmsnorm(x, ln1_w) split
    rmsnorm_split_k<<<T_TOK, b256, 0, stream>>>(x, ln1w, h_hi, h_lo);
    // 2. qkv_w -> transposed split f16
    transpose_split2<<<dim3(QKV_N / 32, HIDN / 32), b256, 0, stream>>>(
        qkvw, qkvwt_h, qkvwt_l, QKV_N, HIDN);
    // 3. qkv = h @ qkv_w + b   (split path)
    gemm_f16<true><<<dim3(QKV_N / 128, T_TOK / 128), b256, 0, stream>>>(
        h_hi, h_lo, qkvwt_h, qkvwt_l, qkvb, nullptr, qkv, nullptr,
        T_TOK, QKV_N, HIDN);
    // 4. k-rmsnorm + rope + split (q pre-scaled)
    qkv_prep<<<T_TOK, b256, 0, stream>>>(qkv, pos, klnw, q_h, q_l, k_h, k_l);
    // 5. v^T: vt[d][t] = qkv[t][2560+d] (split)
    transpose_split2<<<dim3(512 / 32, T_TOK / 32), b256, 0, stream>>>(
        qkv + 2560, vt_h, vt_l, QKV_N, T_TOK);
    // 6. o_w transpose
    transpose_split2<<<dim3(HIDN / 32, HIDN / 32), b256, 0, stream>>>(
        ow, owt_h, owt_l, HIDN, HIDN);
    // 7. attention
    attn_kernel<<<dim3(32, NH), b256, 0, stream>>>(
        q_h, q_l, k_h, k_l, vt_h, vt_l, attn_h, attn_l);
    // 8. x2 = x + attn @ o_w   (split path)
    gemm_f16<true><<<dim3(HIDN / 128, T_TOK / 128), b256, 0, stream>>>(
        attn_h, attn_l, owt_h, owt_l, nullptr, x, x2, nullptr,
        T_TOK, HIDN, HIDN);
    // 9. router -> combine weights
    router_kernel<<<T_TOK, b256, 0, stream>>>(x2, ln2w, rw, combine);
    // 10. h2 = rmsnorm(x2, ln2_w), single f16
    rmsnorm_split_k<<<T_TOK, b256, 0, stream>>>(x2, ln2w, h2, nullptr);
    // 11. W13t: [sw1 | w1[e]... | sw3 | w3[e]...] transposed
    transpose_f16<<<dim3(1024 / 64, HIDN / 32), b256, 0, stream>>>(
        sw1, W13t, 1024, HIDN);
    for (int e = 0; e < NEXP; ++e)
        transpose_f16<<<dim3(512 / 64, HIDN / 32), b256, 0, stream>>>(
            w1 + (size_t)e * HIDN * 512, W13t + (size_t)(1024 + 512 * e) * HIDN,
            512, HIDN);
    transpose_f16<<<dim3(1024 / 64, HIDN / 32), b256, 0, stream>>>(
        sw3, W13t + (size_t)5120 * HIDN, 1024, HIDN);
    for (int e = 0; e < NEXP; ++e)
        transpose_f16<<<dim3(512 / 64, HIDN / 32), b256, 0, stream>>>(
            w3 + (size_t)e * HIDN * 512, W13t + (size_t)(6144 + 512 * e) * HIDN,
            512, HIDN);
    // 12. GU = h2 @ [W1|W3]  (single f16, f16 out)
    gemm_f16<false><<<dim3(10240 / 128, T_TOK / 128), b256, 0, stream>>>(
        h2, nullptr, W13t, nullptr, nullptr, nullptr, nullptr, GU,
        T_TOK, 10240, HIDN);
    // 13. W2t (overwrites dead W13t region)
    transpose_f16<<<dim3(HIDN / 64, 1024 / 32), b256, 0, stream>>>(
        sw2, W2t, HIDN, 5120);
    for (int e = 0; e < NEXP; ++e)
        transpose_f16<<<dim3(HIDN / 64, 512 / 32), b256, 0, stream>>>(
            w2 + (size_t)e * 512 * HIDN, W2t + 1024 + 512 * e, HIDN, 5120);
    // 14. Abig = combine-scaled silu(G)*U
    moe_act<<<(T_TOK * 640) / 256, b256, 0, stream>>>(GU, combine, Abig);
    // 15. out = x2 + Abig @ W2cat
    gemm_f16<false><<<dim3(HIDN / 128, T_TOK / 128), b256, 0, stream>>>(
        Abig, nullptr, W2t, nullptr, nullptr, x2, out, nullptr,
        T_TOK, HIDN, 5120);
}

// Round 3
// 643.645 us; speedup vs baseline: 1.4029x; 1.4029x over previous
//
#include <hip/hip_runtime.h>

// ---------------------------------------------------------------------------
// PanguProMoE decoder layer, MI355X (gfx950).
// Precision: pre-router chain (qkv GEMM, attention, o-proj) in split-f16
// ("f16x2": x = hi + lo/1024, 3 MFMAs/tile) for fp32-grade router logits.
// Post-router MoE in plain f16 MFMA. RoPE angles in double.
// R3: attn prefetch in NAMED registers (R2's uint4 arrays were demoted to
// scratch: VGPR 108->92, WRITE_SIZE 16->130MB -- rule #20); batched W13/W2
// transposes (18 launches -> 2); GEMM BM=64 variant for small-grid GEMMs
// (o-proj/down-proj were 1 block/CU).
// ---------------------------------------------------------------------------

typedef _Float16 half_t;
typedef _Float16 half8 __attribute__((ext_vector_type(8)));
typedef float    f32x4 __attribute__((ext_vector_type(4)));
typedef float    floatx4 __attribute__((ext_vector_type(4)));

#define T_TOK 2048
#define HIDN  2048
#define NH    16
#define NKVH  4
#define HD    128
#define QKV_N 3072
#define NEXP  8

#define MFMA16(a,b,c) __builtin_amdgcn_mfma_f32_16x16x32_f16(a,b,c,0,0,0)

__device__ __forceinline__ void gload_lds16(const half_t* g, half_t* l) {
    __builtin_amdgcn_global_load_lds(
        (const __attribute__((address_space(1))) void*)g,
        (__attribute__((address_space(3))) void*)l, 16, 0, 0);
}

// ---------------------------------------------------------------------------
// rmsnorm over HIDN cols, write split f16 (lo optional)
// ---------------------------------------------------------------------------
__global__ __launch_bounds__(256)
void rmsnorm_split_k(const float* __restrict__ x, const float* __restrict__ w,
                     half_t* __restrict__ hi, half_t* __restrict__ lo)
{
    const int row = blockIdx.x, tid = threadIdx.x;
    const float* xr = x + (size_t)row * HIDN;
    floatx4 v0 = *(const floatx4*)(xr + tid * 8);
    floatx4 v1 = *(const floatx4*)(xr + tid * 8 + 4);
    float ss = v0[0]*v0[0] + v0[1]*v0[1] + v0[2]*v0[2] + v0[3]*v0[3]
             + v1[0]*v1[0] + v1[1]*v1[1] + v1[2]*v1[2] + v1[3]*v1[3];
    for (int o = 32; o; o >>= 1) ss += __shfl_down(ss, o);
    __shared__ float red[4];
    if ((tid & 63) == 0) red[tid >> 6] = ss;
    __syncthreads();
    ss = red[0] + red[1] + red[2] + red[3];
    float rs = rsqrtf(ss * (1.0f / HIDN) + 1e-6f);
    floatx4 w0 = *(const floatx4*)(w + tid * 8);
    floatx4 w1 = *(const floatx4*)(w + tid * 8 + 4);
    float vv[8] = { v0[0]*w0[0], v0[1]*w0[1], v0[2]*w0[2], v0[3]*w0[3],
                    v1[0]*w1[0], v1[1]*w1[1], v1[2]*w1[2], v1[3]*w1[3] };
    half8 hv, lv;
#pragma unroll
    for (int j = 0; j < 8; ++j) {
        float o = vv[j] * rs;
        half_t h = (half_t)o;
        hv[j] = h;
        lv[j] = (half_t)((o - (float)h) * 1024.0f);
    }
    *(half8*)(hi + (size_t)row * HIDN + tid * 8) = hv;
    if (lo) *(half8*)(lo + (size_t)row * HIDN + tid * 8) = lv;
}

// ---------------------------------------------------------------------------
// Transpose fp32 -> split f16: dst[n][k] = src[k][n]. 32x32 tile, half8 writes.
// ---------------------------------------------------------------------------
__global__ __launch_bounds__(256)
void transpose_split2(const float* __restrict__ src, half_t* __restrict__ dh,
                      half_t* __restrict__ dl, int sstride, int dstride)
{
    __shared__ float tile[32][36];
    const int n0 = blockIdx.x * 32, k0 = blockIdx.y * 32;
    const int tid = threadIdx.x;
    {
        int r = tid >> 3, c = (tid & 7) * 4;
        *(floatx4*)&tile[r][c] =
            *(const floatx4*)(src + (size_t)(k0 + r) * sstride + n0 + c);
    }
    __syncthreads();
    int n = tid & 31, g = tid >> 5, gg = g & 3;
    half8 hv;
    if (g < 4) {
#pragma unroll
        for (int j = 0; j < 8; ++j) hv[j] = (half_t)tile[gg * 8 + j][n];
        *(half8*)(dh + (size_t)(n0 + n) * dstride + k0 + gg * 8) = hv;
    } else {
#pragma unroll
        for (int j = 0; j < 8; ++j) {
            float v = tile[gg * 8 + j][n];
            half_t h = (half_t)v;
            hv[j] = (half_t)((v - (float)h) * 1024.0f);
        }
        *(half8*)(dl + (size_t)(n0 + n) * dstride + k0 + gg * 8) = hv;
    }
}

// ---------------------------------------------------------------------------
// Batched W13 transpose: W13t[n][k] (n<10240, k<2048), f16.
// n<1024: sw1[k][n]; n<5120: w1[e][k][c]; n<6144: sw3[k][n-5120];
// else w3[e][k][c].  Tile 32(k) x 64(n); segments 512-aligned, no straddle.
// ---------------------------------------------------------------------------
__global__ __launch_bounds__(256)
void w13_transpose(const float* __restrict__ sw1, const float* __restrict__ w1,
                   const float* __restrict__ sw3, const float* __restrict__ w3,
                   half_t* __restrict__ dst)
{
    __shared__ float tile[32][68];
    const int n0 = blockIdx.x * 64, k0 = blockIdx.y * 32;
    const int tid = threadIdx.x;
    const float* base;
    int stride;
    if (n0 < 1024)      { base = sw1 + n0; stride = 1024; }
    else if (n0 < 5120) { int e = (n0 - 1024) >> 9;
                          base = w1 + (size_t)e * HIDN * 512 + ((n0 - 1024) & 511);
                          stride = 512; }
    else if (n0 < 6144) { base = sw3 + (n0 - 5120); stride = 1024; }
    else                { int e = (n0 - 6144) >> 9;
                          base = w3 + (size_t)e * HIDN * 512 + ((n0 - 6144) & 511);
                          stride = 512; }
    {
        int r = tid >> 3, c = (tid & 7) * 4;
        const float* s = base + (size_t)(k0 + r) * stride;
        *(floatx4*)&tile[r][c]      = *(const floatx4*)(s + c);
        *(floatx4*)&tile[r][c + 32] = *(const floatx4*)(s + c + 32);
    }
    __syncthreads();
    int n = tid & 63, g = tid >> 6;
    half8 hv;
#pragma unroll
    for (int j = 0; j < 8; ++j) hv[j] = (half_t)tile[g * 8 + j][n];
    *(half8*)(dst + (size_t)(n0 + n) * HIDN + k0 + g * 8) = hv;
}

// ---------------------------------------------------------------------------
// Batched W2 transpose: W2t[n][k] (n<2048, k<5120), f16, dstride 5120.
// k<1024: sw2[k][n] ; else w2[e][(k-1024)&511][n].
// ---------------------------------------------------------------------------
__global__ __launch_bounds__(256)
void w2_transpose(const float* __restrict__ sw2, const float* __restrict__ w2,
                  half_t* __restrict__ dst)
{
    __shared__ float tile[32][68];
    const int n0 = blockIdx.x * 64, k0 = blockIdx.y * 32;
    const int tid = threadIdx.x;
    {
        int r = tid >> 3, c = (tid & 7) * 4;
        int k = k0 + r;
        const float* s;
        if (k < 1024) s = sw2 + (size_t)k * HIDN + n0;
        else {
            int e = (k - 1024) >> 9, kk = (k - 1024) & 511;
            s = w2 + ((size_t)e * 512 + kk) * HIDN + n0;
        }
        *(floatx4*)&tile[r][c]      = *(const floatx4*)(s + c);
        *(floatx4*)&tile[r][c + 32] = *(const floatx4*)(s + c + 32);
    }
    __syncthreads();
    int n = tid & 63, g = tid >> 6;
    half8 hv;
#pragma unroll
    for (int j = 0; j < 8; ++j) hv[j] = (half_t)tile[g * 8 + j][n];
    *(half8*)(dst + (size_t)(n0 + n) * 5120 + k0 + g * 8) = hv;
}

// ---------------------------------------------------------------------------
// GEMM: C[M][N] = A[M][K] @ Bt[N][K]^T (+bias)(+res). f16 in, fp32 acc.
// SPLIT: (hi, lo*1024) pairs, 3 MFMAs/tile. BM x 128 tile, BK=32, 4 waves.
// Staging via global_load_lds width=16 into linear LDS (m97 pattern).
// BM=64 for small-grid GEMMs (3 blocks/CU), BM=128 for big N.
// ---------------------------------------------------------------------------
template<bool SPLIT, int BM>
__global__ __launch_bounds__(256, 2)
void gemm_f16(const half_t* __restrict__ Ah, const half_t* __restrict__ Al,
              const half_t* __restrict__ Bth, const half_t* __restrict__ Btl,
              const float* __restrict__ bias, const float* __restrict__ res,
              float* __restrict__ Cf, half_t* __restrict__ Ch,
              int M, int N, int K)
{
    constexpr int NBUF = SPLIT ? 2 : 1;
    constexpr int MR = BM / 32;                  // m-frags per wave
    __shared__ half_t As[NBUF][BM * 32];
    __shared__ half_t Bs[NBUF][128 * 32];
    const int tid = threadIdx.x, lane = tid & 63, wid = tid >> 6;
    const int l15 = lane & 15, l4 = lane >> 4;
    const int row0 = blockIdx.y * BM, col0 = blockIdx.x * 128;
    const int wr = (wid >> 1) * (BM / 2), wc = (wid & 1) * 64;
    f32x4 accM[MR][4] = {}, accC[MR][4] = {};
    const int lrw = lane >> 2, lcl = (lane & 3) * 8;

    for (int k0 = 0; k0 < K; k0 += 32) {
        __syncthreads();
#pragma unroll
        for (int j = 0; j < BM / 64; ++j) {      // stage A
            const int r = wid * (BM / 4) + j * 16;   // wave-uniform base row
            const size_t ga = (size_t)(row0 + r + lrw) * K + k0 + lcl;
            gload_lds16(Ah + ga, &As[0][r * 32]);
            if constexpr (SPLIT) gload_lds16(Al + ga, &As[1][r * 32]);
        }
#pragma unroll
        for (int j = 0; j < 2; ++j) {            // stage B (always 128 rows)
            const int r = wid * 32 + j * 16;
            const size_t gb = (size_t)(col0 + r + lrw) * K + k0 + lcl;
            gload_lds16(Bth + gb, &Bs[0][r * 32]);
            if constexpr (SPLIT) gload_lds16(Btl + gb, &Bs[1][r * 32]);
        }
        __syncthreads();                         // vmcnt(0) drained before barrier
        half8 ah[MR], al[MR], bh[4], bl[4];
#pragma unroll
        for (int m = 0; m < MR; ++m) {
            int off = (wr + m * 16 + l15) * 32 + l4 * 8;
            ah[m] = *(const half8*)&As[0][off];
            if constexpr (SPLIT) al[m] = *(const half8*)&As[1][off];
        }
#pragma unroll
        for (int n = 0; n < 4; ++n) {
            int off = (wc + n * 16 + l15) * 32 + l4 * 8;
            bh[n] = *(const half8*)&Bs[0][off];
            if constexpr (SPLIT) bl[n] = *(const half8*)&Bs[1][off];
        }
#pragma unroll
        for (int m = 0; m < MR; ++m)
#pragma unroll
            for (int n = 0; n < 4; ++n) {
                accM[m][n] = MFMA16(ah[m], bh[n], accM[m][n]);
                if constexpr (SPLIT) {
                    accC[m][n] = MFMA16(ah[m], bl[n], accC[m][n]);
                    accC[m][n] = MFMA16(al[m], bh[n], accC[m][n]);
                }
            }
    }
#pragma unroll
    for (int m = 0; m < MR; ++m) {
#pragma unroll
        for (int n = 0; n < 4; ++n) {
            int gr0 = row0 + wr + m * 16 + l4 * 4;
            int gc  = col0 + wc + n * 16 + l15;
            float b = bias ? bias[gc] : 0.0f;
#pragma unroll
            for (int i = 0; i < 4; ++i) {
                float v = accM[m][n][i];
                if constexpr (SPLIT) v += accC[m][n][i] * (1.0f / 1024.0f);
                v += b;
                size_t idx = (size_t)(gr0 + i) * N + gc;
                if (res) v += res[idx];
                if (Cf) Cf[idx] = v;
                if (Ch) Ch[idx] = (half_t)v;
            }
        }
    }
}

// ---------------------------------------------------------------------------
// qkv post-processing: k-rmsnorm, RoPE on q/k (last 64 dims), Q pre-scaled by
// 128^-0.5, split-f16 outputs.
// ---------------------------------------------------------------------------
__global__ __launch_bounds__(256)
void qkv_prep(const float* __restrict__ qkv, const int* __restrict__ pos,
              const float* __restrict__ klnw,
              half_t* __restrict__ qh, half_t* __restrict__ ql,
              half_t* __restrict__ kh, half_t* __restrict__ kl)
{
    const int t = blockIdx.x, tid = threadIdx.x, lane = tid & 63, wid = tid >> 6;
    const float* row = qkv + (size_t)t * QKV_N;
    __shared__ float cs[32], sn[32];
    if (tid < 32) {
        double freq = exp((double)tid * -0.28782313662425572);  // -ln(1e4)/32
        double ang = (double)pos[t] * freq;
        const double twopi = 6.283185307179586476925286766559;
        ang -= twopi * floor(ang * (1.0 / twopi));
        float a = (float)ang;
        cs[tid] = cosf(a);
        sn[tid] = sinf(a);
    }
    __syncthreads();

    const float qscale = 0.08838834764831845f;   // 128^-0.5
    {
        const int hh = tid >> 4, d0 = (tid & 15) * 8;
        const float* qrow = row + hh * HD;
        float outv[8];
        if (d0 < 64) {
#pragma unroll
            for (int j = 0; j < 8; ++j) outv[j] = qrow[d0 + j];
        } else if (d0 < 96) {
            int j0 = d0 - 64;
#pragma unroll
            for (int j = 0; j < 8; ++j) {
                int jj = j0 + j;
                outv[j] = qrow[64 + jj] * cs[jj] - qrow[96 + jj] * sn[jj];
            }
        } else {
            int j0 = d0 - 96;
#pragma unroll
            for (int j = 0; j < 8; ++j) {
                int jj = j0 + j;
                outv[j] = qrow[64 + jj] * sn[jj] + qrow[96 + jj] * cs[jj];
            }
        }
        half8 hv, lv;
#pragma unroll
        for (int j = 0; j < 8; ++j) {
            float o = outv[j] * qscale;
            half_t h = (half_t)o;
            hv[j] = h;
            lv[j] = (half_t)((o - (float)h) * 1024.0f);
        }
        size_t base = (size_t)t * (NH * HD) + hh * HD + d0;
        *(half8*)(qh + base) = hv;
        *(half8*)(ql + base) = lv;
    }
    {
        const float* krow = row + NH * HD + wid * HD;
        float a0 = krow[lane], a1 = krow[64 + lane];
        float ss = a0 * a0 + a1 * a1;
        for (int o = 32; o; o >>= 1) ss += __shfl_down(ss, o);
        ss = __shfl(ss, 0);
        float rs = rsqrtf(ss * (1.0f / HD) + 1e-6f);
        float n0 = a0 * rs * klnw[lane];
        float n1 = a1 * rs * klnw[64 + lane];
        float other = __shfl_xor(n1, 32);
        int j = lane & 31;
        float o1 = (lane < 32) ? (n1 * cs[j] - other * sn[j])
                               : (other * sn[j] + n1 * cs[j]);
        size_t base = (size_t)t * (NKVH * HD) + wid * HD;
        half_t h;
        h = (half_t)n0; kh[base + lane] = h;
        kl[base + lane] = (half_t)((n0 - (float)h) * 1024.0f);
        h = (half_t)o1; kh[base + 64 + lane] = h;
        kl[base + 64 + lane] = (half_t)((o1 - (float)h) * 1024.0f);
    }
}

// ---------------------------------------------------------------------------
// Flash attention, causal GQA, split-f16 MFMA. 4 waves x 16 q-rows, KVBLK=32.
// LPT-complementary block map; NAMED-register prefetch (no arrays -> no
// scratch demotion); defer-max.
// ---------------------------------------------------------------------------
__global__ __launch_bounds__(256, 2)
void attn_kernel(const half_t* __restrict__ qh, const half_t* __restrict__ ql,
                 const half_t* __restrict__ kh, const half_t* __restrict__ kl,
                 const half_t* __restrict__ vth, const half_t* __restrict__ vtl,
                 half_t* __restrict__ oh, half_t* __restrict__ ol)
{
    const int bid = blockIdx.y * 32 + blockIdx.x;
    int qblk, h;
    if (bid < 256) { qblk = 31 - (bid & 31); h = bid >> 5; }
    else           { qblk = (bid - 256) & 31; h = 8 + ((bid - 256) >> 5); }
    const int kvh = h >> 2;
    const int tid = threadIdx.x, lane = tid & 63, wid = tid >> 6;
    const int q0 = qblk * 64 + wid * 16;
    const int l15 = lane & 15, l4 = lane >> 4;

    __shared__ half_t Ksh[32][136], Ksl[32][136];
    __shared__ half_t Vsh[128][40], Vsl[128][40];
    __shared__ half_t Ph[4][16][40], Pl[4][16][40];

    half8 qfh[4], qfl[4];
    {
        const size_t qb = (size_t)(q0 + l15) * (NH * HD) + h * HD + l4 * 8;
#pragma unroll
        for (int c = 0; c < 4; ++c) {
            qfh[c] = *(const half8*)(qh + qb + c * 32);
            qfl[c] = *(const half8*)(ql + qb + c * 32);
        }
    }

    f32x4 om[8] = {}, oc[8] = {};
    float mrow[4] = { -1e30f, -1e30f, -1e30f, -1e30f };
    float lrow[4] = {};

    const int kr = tid >> 4, kc = (tid & 15) * 8;
    const int vd = tid >> 2, vc = (tid & 3) * 8;
    // NAMED prefetch registers (arrays here get demoted to scratch - rule #20)
    uint4 rk0h, rk1h, rk0l, rk1l, rv0h, rv1h, rv0l, rv1l;

    const int kvend = qblk * 64 + 64;

#define LOAD_TILE(KV0)                                                        \
    do {                                                                      \
        size_t sk0 = (size_t)((KV0) + kr) * (NKVH * HD) + kvh * HD + kc;      \
        size_t sk1 = sk0 + (size_t)16 * (NKVH * HD);                          \
        rk0h = *(const uint4*)(kh + sk0);  rk0l = *(const uint4*)(kl + sk0);  \
        rk1h = *(const uint4*)(kh + sk1);  rk1l = *(const uint4*)(kl + sk1);  \
        size_t sv0 = (size_t)(kvh * HD + vd) * T_TOK + (KV0) + vc;            \
        size_t sv1 = sv0 + (size_t)64 * T_TOK;                                \
        rv0h = *(const uint4*)(vth + sv0); rv0l = *(const uint4*)(vtl + sv0); \
        rv1h = *(const uint4*)(vth + sv1); rv1l = *(const uint4*)(vtl + sv1); \
    } while (0)

    LOAD_TILE(0);
    for (int kv0 = 0; kv0 < kvend; kv0 += 32) {
        *(uint4*)&Ksh[kr][kc]      = rk0h;  *(uint4*)&Ksl[kr][kc]      = rk0l;
        *(uint4*)&Ksh[kr + 16][kc] = rk1h;  *(uint4*)&Ksl[kr + 16][kc] = rk1l;
        *(uint4*)&Vsh[vd][vc]      = rv0h;  *(uint4*)&Vsl[vd][vc]      = rv0l;
        *(uint4*)&Vsh[vd + 64][vc] = rv1h;  *(uint4*)&Vsl[vd + 64][vc] = rv1l;
        __syncthreads();
        if (kv0 + 32 < kvend) LOAD_TILE(kv0 + 32);   // overlaps compute

        f32x4 sf[2];
#pragma unroll
        for (int t2 = 0; t2 < 2; ++t2) {       // S = Q K^T (pre-scaled Q)
            f32x4 s = {}, sc = {};
#pragma unroll
            for (int c = 0; c < 4; ++c) {
                half8 bh = *(const half8*)&Ksh[t2 * 16 + l15][c * 32 + l4 * 8];
                half8 bl = *(const half8*)&Ksl[t2 * 16 + l15][c * 32 + l4 * 8];
                s  = MFMA16(qfh[c], bh, s);
                sc = MFMA16(qfh[c], bl, sc);
                sc = MFMA16(qfl[c], bh, sc);
            }
            sf[t2] = s + sc * (1.0f / 1024.0f);
        }

        float pmax[4];
#pragma unroll
        for (int i = 0; i < 4; ++i) {
            const int qg = q0 + l4 * 4 + i;
#pragma unroll
            for (int t2 = 0; t2 < 2; ++t2) {
                int kvg = kv0 + t2 * 16 + l15;
                if (kvg > qg) sf[t2][i] = -1e30f;
            }
            float mx = fmaxf(sf[0][i], sf[1][i]);
#pragma unroll
            for (int o = 1; o < 16; o <<= 1) mx = fmaxf(mx, __shfl_xor(mx, o));
            pmax[i] = mx;
        }
        float dm = fmaxf(fmaxf(pmax[0] - mrow[0], pmax[1] - mrow[1]),
                         fmaxf(pmax[2] - mrow[2], pmax[3] - mrow[3]));
        if (__any(dm > 6.0f)) {                // defer-max: rescale rarely
#pragma unroll
            for (int i = 0; i < 4; ++i) {
                float mnew = fmaxf(mrow[i], pmax[i]);
                float resc = expf(mrow[i] - mnew);
                lrow[i] *= resc;
#pragma unroll
                for (int c8 = 0; c8 < 8; ++c8) {
                    om[c8][i] *= resc; oc[c8][i] *= resc;
                }
                mrow[i] = mnew;
            }
        }
#pragma unroll
        for (int i = 0; i < 4; ++i) {
            float p0 = expf(sf[0][i] - mrow[i]);
            float p1 = expf(sf[1][i] - mrow[i]);
            lrow[i] += p0 + p1;
            half_t hh;
            hh = (half_t)p0;
            Ph[wid][l4 * 4 + i][l15] = hh;
            Pl[wid][l4 * 4 + i][l15] = (half_t)((p0 - (float)hh) * 1024.0f);
            hh = (half_t)p1;
            Ph[wid][l4 * 4 + i][16 + l15] = hh;
            Pl[wid][l4 * 4 + i][16 + l15] = (half_t)((p1 - (float)hh) * 1024.0f);
        }

        half8 pah = *(const half8*)&Ph[wid][l15][l4 * 8];
        half8 pal = *(const half8*)&Pl[wid][l15][l4 * 8];
#pragma unroll
        for (int c8 = 0; c8 < 8; ++c8) {       // O += P V
            half8 vh = *(const half8*)&Vsh[c8 * 16 + l15][l4 * 8];
            half8 vl = *(const half8*)&Vsl[c8 * 16 + l15][l4 * 8];
            om[c8] = MFMA16(pah, vh, om[c8]);
            oc[c8] = MFMA16(pah, vl, oc[c8]);
            oc[c8] = MFMA16(pal, vh, oc[c8]);
        }
        __syncthreads();
    }
#undef LOAD_TILE

#pragma unroll
    for (int i = 0; i < 4; ++i)
#pragma unroll
        for (int o = 1; o < 16; o <<= 1) lrow[i] += __shfl_xor(lrow[i], o);

#pragma unroll
    for (int c8 = 0; c8 < 8; ++c8) {
#pragma unroll
        for (int i = 0; i < 4; ++i) {
            float v = (om[c8][i] + oc[c8][i] * (1.0f / 1024.0f)) / lrow[i];
            size_t idx = (size_t)(q0 + l4 * 4 + i) * (NH * HD) + h * HD + c8 * 16 + l15;
            half_t hh = (half_t)v;
            oh[idx] = hh;
            ol[idx] = (half_t)((v - (float)hh) * 1024.0f);
        }
    }
}

// ---------------------------------------------------------------------------
// Router: h2 = rmsnorm(x2, ln2w); logits = h2 @ rw; top-2 normalized weights.
// ---------------------------------------------------------------------------
__global__ __launch_bounds__(256)
void router_kernel(const float* __restrict__ x2, const float* __restrict__ ln2w,
                   const float* __restrict__ rw, float* __restrict__ combine)
{
    const int t = blockIdx.x, tid = threadIdx.x;
    const float* xr = x2 + (size_t)t * HIDN;
    float vals[8];
    float ss = 0.0f;
#pragma unroll
    for (int i = 0; i < 8; ++i) {
        vals[i] = xr[tid + i * 256];
        ss += vals[i] * vals[i];
    }
    for (int o = 32; o; o >>= 1) ss += __shfl_down(ss, o);
    __shared__ float red[4];
    if ((tid & 63) == 0) red[tid >> 6] = ss;
    __syncthreads();
    ss = red[0] + red[1] + red[2] + red[3];
    float rs = rsqrtf(ss * (1.0f / HIDN) + 1e-6f);

    float acc[NEXP] = {};
#pragma unroll
    for (int i = 0; i < 8; ++i) {
        int c = tid + i * 256;
        float hv = vals[i] * rs * ln2w[c];
        const float* wr = rw + (size_t)c * NEXP;
#pragma unroll
        for (int e = 0; e < NEXP; ++e) acc[e] += hv * wr[e];
    }
#pragma unroll
    for (int e = 0; e < NEXP; ++e)
        for (int o = 32; o; o >>= 1) acc[e] += __shfl_down(acc[e], o);
    __shared__ float red8[4][NEXP];
    if ((tid & 63) == 0)
#pragma unroll
        for (int e = 0; e < NEXP; ++e) red8[tid >> 6][e] = acc[e];
    __syncthreads();
    if (tid == 0) {
        float lg[NEXP];
#pragma unroll
        for (int e = 0; e < NEXP; ++e)
            lg[e] = red8[0][e] + red8[1][e] + red8[2][e] + red8[3][e];
        int i1 = 0;
        for (int e = 1; e < NEXP; ++e) if (lg[e] > lg[i1]) i1 = e;
        int i2 = (i1 == 0) ? 1 : 0;
        for (int e = 0; e < NEXP; ++e) if (e != i1 && lg[e] > lg[i2]) i2 = e;
        float mx = lg[i1];
        float p1 = expf(lg[i1] - mx), p2 = expf(lg[i2] - mx);
        float inv = 1.0f / (p1 + p2);
        float* cr = combine + (size_t)t * NEXP;
#pragma unroll
        for (int e = 0; e < NEXP; ++e) cr[e] = 0.0f;
        cr[i1] = p1 * inv;
        cr[i2] = p2 * inv;
    }
}

// ---------------------------------------------------------------------------
// MoE activation: Abig[t][n] = scale * silu(G[t][n]) * U[t][n]
// ---------------------------------------------------------------------------
__global__ __launch_bounds__(256)
void moe_act(const half_t* __restrict__ GU, const float* __restrict__ comb,
             half_t* __restrict__ Abig)
{
    int idx = blockIdx.x * 256 + threadIdx.x;
    int t = idx / 640, c8 = idx % 640;
    int n = c8 * 8;
    half8 g8 = *(const half8*)(GU + (size_t)t * 10240 + n);
    half8 u8 = *(const half8*)(GU + (size_t)t * 10240 + 5120 + n);
    float sc = (n < 1024) ? 1.0f : comb[(size_t)t * NEXP + ((n - 1024) >> 9)];
    half8 o8;
#pragma unroll
    for (int j = 0; j < 8; ++j) {
        float g = (float)g8[j], u = (float)u8[j];
        float s = g / (1.0f + expf(-g));
        o8[j] = (half_t)(s * u * sc);
    }
    *(half8*)(Abig + (size_t)t * 5120 + n) = o8;
}

// ---------------------------------------------------------------------------
extern "C" void kernel_launch(void* const* d_in, const int* in_sizes, int n_in,
                              void* d_out, int out_size, void* d_ws, size_t ws_size,
                              hipStream_t stream)
{
    (void)in_sizes; (void)n_in; (void)out_size; (void)ws_size;
    const float* x    = (const float*)d_in[0];
    const int*   pos  = (const int*)  d_in[1];
    const float* ln1w = (const float*)d_in[2];
    const float* qkvw = (const float*)d_in[3];
    const float* qkvb = (const float*)d_in[4];
    const float* klnw = (const float*)d_in[5];
    const float* ow   = (const float*)d_in[6];
    const float* ln2w = (const float*)d_in[7];
    const float* rw   = (const float*)d_in[8];
    const float* w1   = (const float*)d_in[9];
    const float* w2   = (const float*)d_in[10];
    const float* w3   = (const float*)d_in[11];
    const float* sw1  = (const float*)d_in[12];
    const float* sw2  = (const float*)d_in[13];
    const float* sw3  = (const float*)d_in[14];
    float* out = (float*)d_out;

    // ---- workspace arena (phase-overlapped; total 142,671,872 B) ----
    char* ws = (char*)d_ws;
    const size_t AB = 16842752;
    float*  x2      = (float*)(ws);
    float*  combine = (float*)(ws + 16777216);
    half_t* h_hi    = (half_t*)(ws + AB);
    half_t* h_lo    = (half_t*)(ws + AB + 8388608);
    half_t* qkvwt_h = (half_t*)(ws + AB + 16777216);
    half_t* qkvwt_l = (half_t*)(ws + AB + 29360128);
    float*  qkv     = (float*)(ws + AB + 41943040);
    half_t* q_h     = (half_t*)(ws + AB + 67108864);
    half_t* q_l     = (half_t*)(ws + AB + 75497472);
    half_t* k_h     = (half_t*)(ws + AB + 83886080);
    half_t* k_l     = (half_t*)(ws + AB + 85983232);
    half_t* vt_h    = (half_t*)(ws + AB + 88080384);
    half_t* vt_l    = (half_t*)(ws + AB + 90177536);
    half_t* attn_h  = (half_t*)(ws + AB);             // reuse h_hi
    half_t* attn_l  = (half_t*)(ws + AB + 8388608);   // reuse h_lo
    half_t* owt_h   = (half_t*)(ws + AB + 16777216);  // reuse qkvwt
    half_t* owt_l   = (half_t*)(ws + AB + 25165824);
    half_t* h2      = (half_t*)(ws + AB + 33554432);
    half_t* W13t    = (half_t*)(ws + AB + 41943040);  // reuse qkv + q (dead)
    half_t* GU      = (half_t*)(ws + AB + 83886080);  // reuse k/vt (dead)
    half_t* Abig    = (half_t*)(ws + AB);             // reuse attn (dead)
    half_t* W2t     = (half_t*)(ws + AB + 41943040);  // reuse W13t (dead)

    dim3 b256(256);

    // 1. h = rmsnorm(x, ln1_w) split
    rmsnorm_split_k<<<T_TOK, b256, 0, stream>>>(x, ln1w, h_hi, h_lo);
    // 2. qkv_w -> transposed split f16
    transpose_split2<<<dim3(QKV_N / 32, HIDN / 32), b256, 0, stream>>>(
        qkvw, qkvwt_h, qkvwt_l, QKV_N, HIDN);
    // 3. qkv = h @ qkv_w + b   (split path)
    gemm_f16<true, 64><<<dim3(QKV_N / 128, T_TOK / 64), b256, 0, stream>>>(
        h_hi, h_lo, qkvwt_h, qkvwt_l, qkvb, nullptr, qkv, nullptr,
        T_TOK, QKV_N, HIDN);
    // 4. k-rmsnorm + rope + split (q pre-scaled)
    qkv_prep<<<T_TOK, b256, 0, stream>>>(qkv, pos, klnw, q_h, q_l, k_h, k_l);
    // 5. v^T: vt[d][t] = qkv[t][2560+d] (split)
    transpose_split2<<<dim3(512 / 32, T_TOK / 32), b256, 0, stream>>>(
        qkv + 2560, vt_h, vt_l, QKV_N, T_TOK);
    // 6. o_w transpose
    transpose_split2<<<dim3(HIDN / 32, HIDN / 32), b256, 0, stream>>>(
        ow, owt_h, owt_l, HIDN, HIDN);
    // 7. attention
    attn_kernel<<<dim3(32, NH), b256, 0, stream>>>(
        q_h, q_l, k_h, k_l, vt_h, vt_l, attn_h, attn_l);
    // 8. x2 = x + attn @ o_w   (split path)
    gemm_f16<true, 64><<<dim3(HIDN / 128, T_TOK / 64), b256, 0, stream>>>(
        attn_h, attn_l, owt_h, owt_l, nullptr, x, x2, nullptr,
        T_TOK, HIDN, HIDN);
    // 9. router -> combine weights
    router_kernel<<<T_TOK, b256, 0, stream>>>(x2, ln2w, rw, combine);
    // 10. h2 = rmsnorm(x2, ln2_w), single f16
    rmsnorm_split_k<<<T_TOK, b256, 0, stream>>>(x2, ln2w, h2, nullptr);
    // 11. W13t batched transpose (1 launch)
    w13_transpose<<<dim3(10240 / 64, HIDN / 32), b256, 0, stream>>>(
        sw1, w1, sw3, w3, W13t);
    // 12. GU = h2 @ [W1|W3]  (single f16, f16 out)
    gemm_f16<false, 128><<<dim3(10240 / 128, T_TOK / 128), b256, 0, stream>>>(
        h2, nullptr, W13t, nullptr, nullptr, nullptr, nullptr, GU,
        T_TOK, 10240, HIDN);
    // 13. W2t batched transpose (1 launch)
    w2_transpose<<<dim3(HIDN / 64, 5120 / 32), b256, 0, stream>>>(sw2, w2, W2t);
    // 14. Abig = combine-scaled silu(G)*U
    moe_act<<<(T_TOK * 640) / 256, b256, 0, stream>>>(GU, combine, Abig);
    // 15. out = x2 + Abig @ W2cat
    gemm_f16<false, 64><<<dim3(HIDN / 128, T_TOK / 64), b256, 0, stream>>>(
        Abig, nullptr, W2t, nullptr, nullptr, x2, out, nullptr,
        T_TOK, HIDN, 5120);
}